// Round 1
// baseline (36427.988 us; speedup 1.0000x reference)
//
#include <hip/hip_runtime.h>

#define SLOPE 0.01f
#define BN_EPS 1e-5f

static constexpr int C = 64;   // all stage output channels

// ---------------------------------------------------------------------------
// Generic direct conv: out(c,s) = lrelu( sum_{ci,taps} affine(in) * w )
// - optional per-input-channel affine (fused BN from previous stage)
// - writes raw-lrelu output
// - accumulates per-output-channel sum/sumsq into stats[c], stats[C+c]
// grid: (DHW/256, C); block 256
// dynamic LDS: [CIN*KSZ weights][2*CIN affine][256][256] reduction
template<int KD,int KH,int KW,int PD,int PH,int PW,int CIN>
__global__ __launch_bounds__(256)
void conv_lrelu_stats(const float* __restrict__ in, const float* __restrict__ w,
                      const float* __restrict__ aff,
                      float* __restrict__ out, float* __restrict__ stats,
                      int D, int H, int W)
{
    constexpr int KSZ = KD*KH*KW;
    const int c   = blockIdx.y;
    const int tid = threadIdx.x;
    const int HW = H*W, DHW = D*HW;
    const int s = blockIdx.x*256 + tid;

    extern __shared__ float lds[];
    float* sw = lds;                 // CIN*KSZ
    float* sa = sw + CIN*KSZ;        // 2*CIN
    float* r0 = sa + 2*CIN;          // 256
    float* r1 = r0 + 256;            // 256

    for (int i = tid; i < CIN*KSZ; i += 256) sw[i] = w[c*CIN*KSZ + i];
    if (aff) { for (int i = tid; i < 2*CIN; i += 256) sa[i] = aff[i]; }
    __syncthreads();

    float val = 0.f;
    if (s < DHW) {
        const int z = s / HW; const int rr = s - z*HW; const int y = rr / W; const int x = rr - y*W;
        bool zok[KD]; int zz[KD];
        bool yok[KH]; int yy[KH];
        bool xok[KW]; int xx[KW];
        #pragma unroll
        for (int k=0;k<KD;++k){ int t=z+k-PD; zok[k]=(t>=0)&&(t<D); zz[k]=t*HW; }
        #pragma unroll
        for (int k=0;k<KH;++k){ int t=y+k-PH; yok[k]=(t>=0)&&(t<H); yy[k]=t*W; }
        #pragma unroll
        for (int k=0;k<KW;++k){ int t=x+k-PW; xok[k]=(t>=0)&&(t<W); xx[k]=t; }

        float acc = 0.f;
        for (int ci=0; ci<CIN; ++ci) {
            const float* ip = in + (size_t)ci*DHW;
            const float* wp = sw + ci*KSZ;
            float sc=1.f, sh=0.f;
            if (aff){ sc=sa[ci]; sh=sa[CIN+ci]; }
            #pragma unroll
            for (int kd=0;kd<KD;++kd) if (zok[kd])
              #pragma unroll
              for (int kh=0;kh<KH;++kh) if (yok[kh])
                #pragma unroll
                for (int kw=0;kw<KW;++kw) if (xok[kw]) {
                    float v = ip[zz[kd]+yy[kh]+xx[kw]];
                    if (aff) v = v*sc + sh;
                    acc += v * wp[(kd*KH+kh)*KW+kw];
                }
        }
        val = (acc >= 0.f) ? acc : SLOPE*acc;
        out[(size_t)c*DHW + s] = val;
    }

    // per-block stats reduction (inactive lanes contribute 0)
    r0[tid] = val; r1[tid] = val*val;
    __syncthreads();
    #pragma unroll
    for (int off=128; off>0; off>>=1) {
        if (tid < off) { r0[tid]+=r0[tid+off]; r1[tid]+=r1[tid+off]; }
        __syncthreads();
    }
    if (tid==0) { atomicAdd(&stats[c], r0[0]); atomicAdd(&stats[C+c], r1[0]); }
}

// stats -> fused affine (scale, shift) for the consumer of this BN
__global__ void finalize_stats(const float* __restrict__ stats, const float* __restrict__ g,
                               const float* __restrict__ b, float invN, float* __restrict__ aff)
{
    int c = threadIdx.x;                    // 64 threads
    float m    = stats[c]*invN;
    float var  = stats[C+c]*invN - m*m;
    float rstd = rsqrtf(var + BN_EPS);
    float sc   = g[c]*rstd;
    aff[c]     = sc;
    aff[C+c]   = b[c] - m*sc;
}

// Transposed conv (lhs_dilation=2, k=3, pad(1,2)) + skip add.
// out[o,z,y,x] = sum_ci sum_{valid taps} w[o,ci,kd,kh,kw] * xtn[ci,(z+kd-1)/2,...]
// tap valid iff dilated index in range and even.
__global__ __launch_bounds__(256)
void tconv_add_skip(const float* __restrict__ xt, const float* __restrict__ w,
                    const float* __restrict__ aff, const float* __restrict__ skip,
                    float* __restrict__ out)
{
    constexpr int D0=16,H0=48,W0=48,D1=32,H1=96,W1=96;
    constexpr int HW0=H0*W0, DHW0=D0*HW0, HW1=H1*W1, DHW1=D1*HW1;
    const int o = blockIdx.y; const int tid = threadIdx.x;
    const int s = blockIdx.x*256 + tid;
    extern __shared__ float lds[];
    float* sw = lds;            // 64*27
    float* sa = sw + C*27;      // 128
    for (int i=tid;i<C*27;i+=256) sw[i]=w[o*C*27+i];
    for (int i=tid;i<2*C;i+=256) sa[i]=aff[i];
    __syncthreads();
    if (s >= DHW1) return;
    const int z=s/HW1; const int r=s-z*HW1; const int y=r/W1; const int x=r-y*W1;

    bool okz[3]; int zo[3];
    bool oky[3]; int yo[3];
    bool okx[3]; int xo[3];
    #pragma unroll
    for (int k=0;k<3;++k){ int dl=z+k-1; bool ok=(dl>=0)&&(dl<=2*D0-2)&&((dl&1)==0); okz[k]=ok; zo[k]= ok?(dl>>1)*HW0:0; }
    #pragma unroll
    for (int k=0;k<3;++k){ int dl=y+k-1; bool ok=(dl>=0)&&(dl<=2*H0-2)&&((dl&1)==0); oky[k]=ok; yo[k]= ok?(dl>>1)*W0:0; }
    #pragma unroll
    for (int k=0;k<3;++k){ int dl=x+k-1; bool ok=(dl>=0)&&(dl<=2*W0-2)&&((dl&1)==0); okx[k]=ok; xo[k]= ok?(dl>>1):0; }

    float acc = 0.f;
    for (int ci=0; ci<C; ++ci) {
        const float* ip = xt + (size_t)ci*DHW0;
        const float* wp = sw + ci*27;
        const float sc = sa[ci], sh = sa[C+ci];
        #pragma unroll
        for (int kd=0;kd<3;++kd) if (okz[kd])
          #pragma unroll
          for (int kh=0;kh<3;++kh) if (oky[kh])
            #pragma unroll
            for (int kw=0;kw<3;++kw) if (okx[kw]) {
                float v = ip[zo[kd]+yo[kh]+xo[kw]]*sc + sh;
                acc += v * wp[kd*9 + kh*3 + kw];
            }
    }
    const size_t idx = (size_t)o*DHW1 + s;
    out[idx] = acc + skip[idx];
}

// final in-place BN on d_out (float4 vectorized)
__global__ __launch_bounds__(256)
void bn_apply(float* __restrict__ buf, const float* __restrict__ aff, int DHW)
{
    const int i = blockIdx.x*256 + threadIdx.x;
    const int c = (i*4) / DHW;
    const float sc = aff[c], sh = aff[C+c];
    float4* p = (float4*)buf;
    float4 v = p[i];
    v.x = v.x*sc+sh; v.y = v.y*sc+sh; v.z = v.z*sc+sh; v.w = v.w*sc+sh;
    p[i] = v;
}

extern "C" void kernel_launch(void* const* d_in, const int* in_sizes, int n_in,
                              void* d_out, int out_size, void* d_ws, size_t ws_size,
                              hipStream_t stream)
{
    const float* x       = (const float*)d_in[0];
    const float* skip    = (const float*)d_in[1];
    const float* w_trans = (const float*)d_in[2];
    const float* g_t     = (const float*)d_in[3];
    const float* b_t     = (const float*)d_in[4];
    const float* w_up    = (const float*)d_in[5];
    const float* w1      = (const float*)d_in[6];
    const float* g1      = (const float*)d_in[7];
    const float* b1      = (const float*)d_in[8];
    const float* w2      = (const float*)d_in[9];
    const float* g2      = (const float*)d_in[10];
    const float* b2      = (const float*)d_in[11];
    const float* w3      = (const float*)d_in[12];
    const float* g3      = (const float*)d_in[13];
    const float* b3      = (const float*)d_in[14];
    float* out = (float*)d_out;

    constexpr int D0=16,H0=48,W0=48,D1=32,H1=96,W1=96;
    constexpr int DHW0 = D0*H0*W0;   // 36864
    constexpr int DHW1 = D1*H1*W1;   // 294912

    char* ws = (char*)d_ws;
    float* bufA  = (float*)ws;                                         // C*DHW1 fp32 (75.5 MB)
    float* y0    = (float*)(ws + (size_t)C*DHW1*4);                    // C*DHW0 fp32 (9.4 MB)
    float* stats = (float*)(ws + (size_t)C*DHW1*4 + (size_t)C*DHW0*4); // 4*128 floats
    float* affs  = stats + 4*2*C;                                      // 4*128 floats

    float* st_t = stats;       float* aff_t = affs;
    float* st_1 = stats+128;   float* aff_1 = affs+128;
    float* st_2 = stats+256;   float* aff_2 = affs+256;
    float* st_3 = stats+384;   float* aff_3 = affs+384;

    hipMemsetAsync(stats, 0, 4*2*C*sizeof(float), stream);

    // stage 1: subm conv 3x3x3 (Cin=128) + lrelu + stats, coarse grid
    {
        dim3 g(DHW0/256, C);
        size_t lds = (128*27 + 2*128 + 512)*sizeof(float);
        conv_lrelu_stats<3,3,3,1,1,1,128><<<g,256,lds,stream>>>(x, w_trans, nullptr, y0, st_t, D0,H0,W0);
        finalize_stats<<<1,C,0,stream>>>(st_t, g_t, b_t, 1.f/DHW0, aff_t);
    }
    // stage 2: transposed conv (BN_t fused on load) + skip -> bufA
    {
        dim3 g(DHW1/256, C);
        size_t lds = (64*27 + 2*64)*sizeof(float);
        tconv_add_skip<<<g,256,lds,stream>>>(y0, w_up, aff_t, skip, bufA);
    }
    // stage 3: conv (1,3,3) pad (0,1,1) + lrelu + stats1 -> d_out (raw lrelu)
    {
        dim3 g(DHW1/256, C);
        size_t lds = (64*9 + 2*64 + 512)*sizeof(float);
        conv_lrelu_stats<1,3,3,0,1,1,64><<<g,256,lds,stream>>>(bufA, w1, nullptr, out, st_1, D1,H1,W1);
        finalize_stats<<<1,C,0,stream>>>(st_1, g1, b1, 1.f/DHW1, aff_1);
    }
    // stage 4: conv (3,1,3) pad (1,0,1), BN1 fused on load -> bufA
    {
        dim3 g(DHW1/256, C);
        size_t lds = (64*9 + 2*64 + 512)*sizeof(float);
        conv_lrelu_stats<3,1,3,1,0,1,64><<<g,256,lds,stream>>>(out, w2, aff_1, bufA, st_2, D1,H1,W1);
        finalize_stats<<<1,C,0,stream>>>(st_2, g2, b2, 1.f/DHW1, aff_2);
    }
    // stage 5: conv (3,3,3) pad 1, BN2 fused on load -> d_out (raw lrelu)
    {
        dim3 g(DHW1/256, C);
        size_t lds = (64*27 + 2*64 + 512)*sizeof(float);
        conv_lrelu_stats<3,3,3,1,1,1,64><<<g,256,lds,stream>>>(bufA, w3, aff_2, out, st_3, D1,H1,W1);
        finalize_stats<<<1,C,0,stream>>>(st_3, g3, b3, 1.f/DHW1, aff_3);
    }
    // stage 6: apply BN3 in place on d_out
    {
        const int n4 = C*DHW1/4;
        bn_apply<<<n4/256, 256, 0, stream>>>(out, aff_3, DHW1);
    }
}

// Round 2
// 1088.994 us; speedup vs baseline: 33.4510x; 33.4510x over previous
//
#include <hip/hip_runtime.h>

#define SLOPE 0.01f
#define BN_EPS 1e-5f

typedef __attribute__((ext_vector_type(8))) short short8;
typedef __attribute__((ext_vector_type(4))) float f32x4;

static constexpr int D1 = 32, H1 = 96, W1_ = 96;
static constexpr int HW1 = H1 * W1_, DHW1 = D1 * HW1;        // 294912
static constexpr int D0 = 16, H0 = 48, W0 = 48;
static constexpr int HW0 = H0 * W0, DHW0 = D0 * HW0;         // 36864

__device__ __forceinline__ short f2bf(float f) {
    unsigned u = __builtin_bit_cast(unsigned, f);
    unsigned r = (u + 0x7fffu + ((u >> 16) & 1u)) >> 16;
    return (short)r;
}
__device__ __forceinline__ float bf2f(short s) {
    unsigned u = ((unsigned)(unsigned short)s) << 16;
    return __builtin_bit_cast(float, u);
}

// ---------------------------------------------------------------------------
// NCDHW fp32 (C x S) -> channels-last bf16 [S][C]; 64x64 tiles via LDS
__global__ __launch_bounds__(256)
void to_cl_bf16(const float* __restrict__ in, short* __restrict__ out, int S, int C)
{
    __shared__ float t[64][65];
    const int s0 = blockIdx.x * 64, c0 = blockIdx.y * 64;
    const int tid = threadIdx.x;
    {
        const int cpr = tid >> 2, ch = tid & 3;
        const float4* ip = (const float4*)(in + (size_t)(c0 + cpr) * S + s0 + ch * 16);
        #pragma unroll
        for (int i = 0; i < 4; ++i) {
            float4 v = ip[i]; int sb = ch * 16 + i * 4;
            t[sb][cpr] = v.x; t[sb + 1][cpr] = v.y; t[sb + 2][cpr] = v.z; t[sb + 3][cpr] = v.w;
        }
    }
    __syncthreads();
    {
        const int spr = tid >> 2, cc = (tid & 3) * 16;
        short8 o0, o1;
        #pragma unroll
        for (int q = 0; q < 8; ++q) { o0[q] = f2bf(t[spr][cc + q]); o1[q] = f2bf(t[spr][cc + 8 + q]); }
        short* op = out + (size_t)(s0 + spr) * C + c0 + cc;
        *(short8*)op = o0;
        *(short8*)(op + 8) = o1;
    }
}

// w OIDHW fp32 [o][ci][t] -> bf16 [t][o][ci]
__global__ __launch_bounds__(256)
void prep_w(const float* __restrict__ w, short* __restrict__ dst, int CIN, int KSZ)
{
    int i = blockIdx.x * 256 + threadIdx.x;
    int n = KSZ * 64 * CIN;
    if (i >= n) return;
    int t = i / (64 * CIN); int r = i % (64 * CIN); int o = r / CIN; int ci = r % CIN;
    dst[i] = f2bf(w[(size_t)(o * CIN + ci) * KSZ + t]);
}

// stats -> fused affine (scale, shift)
__global__ void finalize_stats(const float* __restrict__ stats, const float* __restrict__ g,
                               const float* __restrict__ b, float invN, float* __restrict__ aff)
{
    int c = threadIdx.x;                    // 64 threads
    float m = stats[c] * invN;
    float var = stats[64 + c] * invN - m * m;
    float rstd = rsqrtf(var + BN_EPS);
    float sc = g[c] * rstd;
    aff[c] = sc;
    aff[64 + c] = b[c] - m * sc;
}

// in-place-safe bf16 affine: v = v*sc[c] + sh[c], channels-last (c = low 6 bits of elem idx)
__global__ __launch_bounds__(256)
void affine_bf16(const short* __restrict__ in, short* __restrict__ out,
                 const float* __restrict__ aff, int n8)
{
    int i = blockIdx.x * 256 + threadIdx.x;
    if (i >= n8) return;
    int cb = (i * 8) & 63;
    short8 v = *(const short8*)(in + (size_t)i * 8);
    short8 o;
    #pragma unroll
    for (int q = 0; q < 8; ++q) {
        int c = cb + q;
        o[q] = f2bf(bf2f(v[q]) * aff[c] + aff[64 + c]);
    }
    *(short8*)(out + (size_t)i * 8) = o;
}

// final: U3raw [S][64] bf16 --aff3--> out NCDHW fp32
__global__ __launch_bounds__(256)
void final_out(const short* __restrict__ in, float* __restrict__ out, const float* __restrict__ aff)
{
    __shared__ float t[64][65];
    const int s0 = blockIdx.x * 64;
    const int tid = threadIdx.x;
    {
        const int spr = tid >> 2, ch = tid & 3;
        const short8* ip = (const short8*)(in + (size_t)(s0 + spr) * 64 + ch * 16);
        short8 v0 = ip[0], v1 = ip[1];
        #pragma unroll
        for (int q = 0; q < 8; ++q) { int c = ch * 16 + q;     t[spr][c] = bf2f(v0[q]) * aff[c] + aff[64 + c]; }
        #pragma unroll
        for (int q = 0; q < 8; ++q) { int c = ch * 16 + 8 + q; t[spr][c] = bf2f(v1[q]) * aff[c] + aff[64 + c]; }
    }
    __syncthreads();
    {
        const int c = tid >> 2, sc = (tid & 3) * 16;
        #pragma unroll
        for (int i = 0; i < 4; ++i) {
            float4 w;
            w.x = t[sc + 4 * i][c]; w.y = t[sc + 4 * i + 1][c];
            w.z = t[sc + 4 * i + 2][c]; w.w = t[sc + 4 * i + 3][c];
            *(float4*)(out + (size_t)c * DHW1 + s0 + sc + 4 * i) = w;
        }
    }
}

// ---------------------------------------------------------------------------
// Implicit-GEMM conv via MFMA. Block: 256 thr = 4 waves; each wave: 32 rows x 64 cols.
// A: [S_in][CIN] bf16 channels-last. Wt: [KSZ][64][CIN] bf16. Out: [S_out][64] bf16.
// TCONV: lhs_dilation=2 gather (A on half-res grid) + skip-add epilogue, no lrelu/stats.
// RELU_STATS: lrelu + per-channel sum/sumsq atomics.
template<int CIN, int KD, int KH, int KW, int PD, int PH, int PW,
         int DD, int HH, int WW, bool TCONV, bool RELU_STATS>
__global__ __launch_bounds__(256)
void convmm(const short* __restrict__ A, const short* __restrict__ Wt,
            const short* __restrict__ SK, short* __restrict__ Out,
            float* __restrict__ stats)
{
    constexpr int KSZ = KD * KH * KW;
    constexpr int HWo = HH * WW;
    constexpr int Din = TCONV ? DD / 2 : DD;
    constexpr int Hin = TCONV ? HH / 2 : HH;
    constexpr int Win = TCONV ? WW / 2 : WW;

    const int tid = threadIdx.x;
    const int lane = tid & 63, wave = tid >> 6;
    const int rl = lane & 15, kg = lane >> 4;
    const int m0 = blockIdx.x * 128 + wave * 32;

    int zz[2], yy[2], xx[2];
    #pragma unroll
    for (int mg = 0; mg < 2; ++mg) {
        int s = m0 + mg * 16 + rl;
        zz[mg] = s / HWo; int r = s % HWo; yy[mg] = r / WW; xx[mg] = r % WW;
    }

    f32x4 acc[2][4];
    #pragma unroll
    for (int mg = 0; mg < 2; ++mg)
        #pragma unroll
        for (int ng = 0; ng < 4; ++ng)
            acc[mg][ng] = (f32x4){0.f, 0.f, 0.f, 0.f};

    const short* bbase = Wt + rl * CIN + kg * 8;
    const short* abase = A + kg * 8;
    const short8 zfrag = {0, 0, 0, 0, 0, 0, 0, 0};

    for (int t = 0; t < KSZ; ++t) {
        const int kd = t / (KH * KW), rt = t % (KH * KW), kh = rt / KW, kw = rt % KW;
        int aoff[2]; bool val[2];
        #pragma unroll
        for (int mg = 0; mg < 2; ++mg) {
            bool ok; int iz, iy, ix;
            if (TCONV) {
                int dl = zz[mg] + kd - 1; bool okz = (dl >= 0) & (dl <= DD - 2) & (!(dl & 1)); iz = dl >> 1;
                int hl = yy[mg] + kh - 1; bool oky = (hl >= 0) & (hl <= HH - 2) & (!(hl & 1)); iy = hl >> 1;
                int wl = xx[mg] + kw - 1; bool okx = (wl >= 0) & (wl <= WW - 2) & (!(wl & 1)); ix = wl >> 1;
                ok = okz & oky & okx;
            } else {
                iz = zz[mg] + kd - PD; iy = yy[mg] + kh - PH; ix = xx[mg] + kw - PW;
                ok = (iz >= 0) & (iz < Din) & (iy >= 0) & (iy < Hin) & (ix >= 0) & (ix < Win);
            }
            val[mg] = ok;
            aoff[mg] = ok ? ((iz * Hin + iy) * Win + ix) * CIN : 0;
        }
        const short* wt_t = bbase + t * 64 * CIN;
        #pragma unroll
        for (int kc = 0; kc < CIN / 32; ++kc) {
            short8 a[2], b[4];
            #pragma unroll
            for (int mg = 0; mg < 2; ++mg)
                a[mg] = val[mg] ? *(const short8*)(abase + aoff[mg] + kc * 32) : zfrag;
            #pragma unroll
            for (int ng = 0; ng < 4; ++ng)
                b[ng] = *(const short8*)(wt_t + ng * 16 * CIN + kc * 32);
            #pragma unroll
            for (int mg = 0; mg < 2; ++mg)
                #pragma unroll
                for (int ng = 0; ng < 4; ++ng)
                    acc[mg][ng] = __builtin_amdgcn_mfma_f32_16x16x32_bf16(a[mg], b[ng], acc[mg][ng], 0, 0, 0);
        }
    }

    // epilogue: stage tile in LDS (bf16), then coalesced global writes (+skip for TCONV)
    __shared__ short tile[128][72];
    __shared__ float red[2][4][64];

    #pragma unroll
    for (int mg = 0; mg < 2; ++mg)
        #pragma unroll
        for (int ng = 0; ng < 4; ++ng)
            #pragma unroll
            for (int j = 0; j < 4; ++j) {
                float v = acc[mg][ng][j];
                if (RELU_STATS) v = (v >= 0.f) ? v : SLOPE * v;
                tile[wave * 32 + mg * 16 + kg * 4 + j][ng * 16 + rl] = f2bf(v);
            }
    __syncthreads();

    const int row0 = blockIdx.x * 128;
    #pragma unroll
    for (int i = 0; i < 4; ++i) {
        int chunk = i * 256 + tid;
        int r = chunk >> 3, cc = (chunk & 7) * 8;
        short8 v = *(const short8*)&tile[r][cc];
        size_t gaddr = (size_t)(row0 + r) * 64 + cc;
        if (TCONV) {
            short8 skv = *(const short8*)(SK + gaddr);
            short8 o;
            #pragma unroll
            for (int q = 0; q < 8; ++q) o[q] = f2bf(bf2f(v[q]) + bf2f(skv[q]));
            *(short8*)(Out + gaddr) = o;
        } else {
            *(short8*)(Out + gaddr) = v;
        }
    }

    if (RELU_STATS) {
        float s1 = 0.f, s2 = 0.f;
        const int col = tid & 63, rg = tid >> 6;
        #pragma unroll 4
        for (int r = rg * 32; r < rg * 32 + 32; ++r) {
            float v = bf2f(tile[r][col]); s1 += v; s2 += v * v;
        }
        red[0][rg][col] = s1; red[1][rg][col] = s2;
        __syncthreads();
        if (tid < 64) {
            float a = red[0][0][tid] + red[0][1][tid] + red[0][2][tid] + red[0][3][tid];
            float b = red[1][0][tid] + red[1][1][tid] + red[1][2][tid] + red[1][3][tid];
            atomicAdd(&stats[tid], a);
            atomicAdd(&stats[64 + tid], b);
        }
    }
}

// ---------------------------------------------------------------------------
extern "C" void kernel_launch(void* const* d_in, const int* in_sizes, int n_in,
                              void* d_out, int out_size, void* d_ws, size_t ws_size,
                              hipStream_t stream)
{
    const float* x       = (const float*)d_in[0];
    const float* skip    = (const float*)d_in[1];
    const float* w_trans = (const float*)d_in[2];
    const float* g_t     = (const float*)d_in[3];
    const float* b_t     = (const float*)d_in[4];
    const float* w_up    = (const float*)d_in[5];
    const float* w1      = (const float*)d_in[6];
    const float* g1      = (const float*)d_in[7];
    const float* b1      = (const float*)d_in[8];
    const float* w2      = (const float*)d_in[9];
    const float* g2      = (const float*)d_in[10];
    const float* b2      = (const float*)d_in[11];
    const float* w3      = (const float*)d_in[12];
    const float* g3      = (const float*)d_in[13];
    const float* b3      = (const float*)d_in[14];
    float* out = (float*)d_out;

    // ws layout (bf16 buffers as short*)
    char* ws = (char*)d_ws;
    constexpr size_t SZ_FINE = (size_t)DHW1 * 64 * 2;   // 37,748,736
    constexpr size_t SZ_COARSE = (size_t)DHW0 * 64 * 2; // 4,718,592
    short* Wb1   = (short*)ws;                      // U1raw/U1, U2raw->.., U3raw
    short* Wb2   = (short*)(ws + SZ_FINE);          // ping-pong partner
    short* Y0    = (short*)(ws + 2 * SZ_FINE);      // coarse stage out (raw -> affined in place)
    char*  wp    = ws + 2 * SZ_FINE + SZ_COARSE;
    short* wt_t  = (short*)wp;                      // 27*64*128
    short* wt_up = (short*)(wp + 442368);           // 27*64*64
    short* wt_1  = (short*)(wp + 442368 + 221184);  // 9*64*64
    short* wt_2  = (short*)(wp + 442368 + 221184 + 73728);
    short* wt_3  = (short*)(wp + 442368 + 221184 + 2 * 73728);
    float* stats = (float*)(wp + 442368 + 2 * 221184 + 2 * 73728);  // 4 x 128 f32
    float* affs  = stats + 4 * 128;                                  // 4 x 128 f32

    float* st0 = stats;       float* af0 = affs;
    float* st1 = stats + 128; float* af1 = affs + 128;
    float* st2 = stats + 256; float* af2 = affs + 256;
    float* st3 = stats + 384; float* af3 = affs + 384;

    // d_out scratch: X0 [0, 9.44M) early; SK [0, 37.75M); U0 [37.75M, 75.5M)
    short* X0 = (short*)d_out;
    short* SKb = (short*)d_out;
    short* U0 = (short*)((char*)d_out + SZ_FINE);

    hipMemsetAsync(stats, 0, 4 * 128 * sizeof(float), stream);

    // weight repacks
    prep_w<<<(27 * 64 * 128 + 255) / 256, 256, 0, stream>>>(w_trans, wt_t, 128, 27);
    prep_w<<<(27 * 64 * 64 + 255) / 256, 256, 0, stream>>>(w_up, wt_up, 64, 27);
    prep_w<<<(9 * 64 * 64 + 255) / 256, 256, 0, stream>>>(w1, wt_1, 64, 9);
    prep_w<<<(9 * 64 * 64 + 255) / 256, 256, 0, stream>>>(w2, wt_2, 64, 9);
    prep_w<<<(27 * 64 * 64 + 255) / 256, 256, 0, stream>>>(w3, wt_3, 64, 27);

    // x -> channels-last bf16 (in d_out scratch)
    to_cl_bf16<<<dim3(DHW0 / 64, 2), 256, 0, stream>>>(x, X0, DHW0, 128);

    // stage A: subm conv 3x3x3 CIN=128 on coarse grid, lrelu+stats
    convmm<128, 3, 3, 3, 1, 1, 1, D0, H0, W0, false, true>
        <<<DHW0 / 128, 256, 0, stream>>>(X0, wt_t, nullptr, Y0, st0);
    finalize_stats<<<1, 64, 0, stream>>>(st0, g_t, b_t, 1.f / DHW0, af0);
    affine_bf16<<<(DHW0 * 64 / 8 + 255) / 256, 256, 0, stream>>>(Y0, Y0, af0, DHW0 * 64 / 8);

    // skip -> channels-last bf16 (overwrites X0 region; X0 dead)
    to_cl_bf16<<<dim3(DHW1 / 64, 1), 256, 0, stream>>>(skip, SKb, DHW1, 64);

    // stage B: transposed conv + skip -> U0
    convmm<64, 3, 3, 3, 1, 1, 1, D1, H1, W1_, true, false>
        <<<DHW1 / 128, 256, 0, stream>>>(Y0, wt_up, SKb, U0, nullptr);

    // stage C: conv (1,3,3) pad (0,1,1)
    convmm<64, 1, 3, 3, 0, 1, 1, D1, H1, W1_, false, true>
        <<<DHW1 / 128, 256, 0, stream>>>(U0, wt_1, nullptr, Wb1, st1);
    finalize_stats<<<1, 64, 0, stream>>>(st1, g1, b1, 1.f / DHW1, af1);
    affine_bf16<<<(DHW1 * 64 / 8 + 255) / 256, 256, 0, stream>>>(Wb1, Wb1, af1, DHW1 * 64 / 8);

    // stage D: conv (3,1,3) pad (1,0,1)
    convmm<64, 3, 1, 3, 1, 0, 1, D1, H1, W1_, false, true>
        <<<DHW1 / 128, 256, 0, stream>>>(Wb1, wt_2, nullptr, Wb2, st2);
    finalize_stats<<<1, 64, 0, stream>>>(st2, g2, b2, 1.f / DHW1, af2);
    affine_bf16<<<(DHW1 * 64 / 8 + 255) / 256, 256, 0, stream>>>(Wb2, Wb2, af2, DHW1 * 64 / 8);

    // stage E: conv (3,3,3) pad 1
    convmm<64, 3, 3, 3, 1, 1, 1, D1, H1, W1_, false, true>
        <<<DHW1 / 128, 256, 0, stream>>>(Wb2, wt_3, nullptr, Wb1, st3);
    finalize_stats<<<1, 64, 0, stream>>>(st3, g3, b3, 1.f / DHW1, af3);

    // final: aff3 + transpose to NCDHW fp32
    final_out<<<DHW1 / 64, 256, 0, stream>>>(Wb1, out, af3);
}

// Round 3
// 709.292 us; speedup vs baseline: 51.3582x; 1.5353x over previous
//
#include <hip/hip_runtime.h>

#define SLOPE 0.01f
#define BN_EPS 1e-5f

typedef __attribute__((ext_vector_type(8))) short short8;
typedef __attribute__((ext_vector_type(4))) float f32x4;

static constexpr int D1 = 32, H1 = 96, W1_ = 96;
static constexpr int HW1 = H1 * W1_, DHW1 = D1 * HW1;        // 294912
static constexpr int D0 = 16, H0 = 48, W0 = 48;
static constexpr int HW0 = H0 * W0, DHW0 = D0 * HW0;         // 36864

// padded geometries (y/x halo of 1, plus one trailing all-zero "trash" z-plane)
static constexpr int FP_PLPTS = 98 * 98;            // 9604 pts per fine padded plane
static constexpr int CP_PLPTS = 50 * 50;            // 2500 pts per coarse padded plane
static constexpr int FP_ELEMS = 33 * FP_PLPTS * 64; // fine padded buffer (planes 0..31 + trash 32)
static constexpr int CPX_ELEMS = 17 * CP_PLPTS * 128; // X0pad (planes 0..15 + trash 16)
static constexpr int CPY_ELEMS = 17 * CP_PLPTS * 64;  // Y0pad

__device__ __forceinline__ short f2bf(float f) {
    unsigned u = __builtin_bit_cast(unsigned, f);
    unsigned r = (u + 0x7fffu + ((u >> 16) & 1u)) >> 16;
    return (short)r;
}
__device__ __forceinline__ float bf2f(short s) {
    unsigned u = ((unsigned)(unsigned short)s) << 16;
    return __builtin_bit_cast(float, u);
}

__device__ __forceinline__ int pidx_fine(int s) {
    int z = s / HW1; int r = s - z * HW1; int y = r / W1_; int x = r - y * W1_;
    return z * FP_PLPTS + (y + 1) * 98 + (x + 1);
}
__device__ __forceinline__ int pidx_coarse(int s) {
    int z = s / HW0; int r = s - z * HW0; int y = r / W0; int x = r - y * W0;
    return z * CP_PLPTS + (y + 1) * 50 + (x + 1);
}

// ---------------------------------------------------------------------------
// x (fp32 NCDHW, C=128, coarse) -> X0pad channels-last bf16 padded
__global__ __launch_bounds__(256)
void to_cl_pad128(const float* __restrict__ in, short* __restrict__ out)
{
    __shared__ float t[64][65];
    const int s0 = blockIdx.x * 64, c0 = blockIdx.y * 64;
    const int tid = threadIdx.x;
    {
        const int cpr = tid >> 2, ch = tid & 3;
        const float4* ip = (const float4*)(in + (size_t)(c0 + cpr) * DHW0 + s0 + ch * 16);
        #pragma unroll
        for (int i = 0; i < 4; ++i) {
            float4 v = ip[i]; int sb = ch * 16 + i * 4;
            t[sb][cpr] = v.x; t[sb + 1][cpr] = v.y; t[sb + 2][cpr] = v.z; t[sb + 3][cpr] = v.w;
        }
    }
    __syncthreads();
    {
        const int spr = tid >> 2, cc = (tid & 3) * 16;
        short8 o0, o1;
        #pragma unroll
        for (int q = 0; q < 8; ++q) { o0[q] = f2bf(t[spr][cc + q]); o1[q] = f2bf(t[spr][cc + 8 + q]); }
        const int p = pidx_coarse(s0 + spr);
        short* op = out + (size_t)p * 128 + c0 + cc;
        *(short8*)op = o0;
        *(short8*)(op + 8) = o1;
    }
}

// skip (fp32 NCDHW, C=64, fine) -> compact channels-last bf16 [S][64]
__global__ __launch_bounds__(256)
void to_cl_bf16(const float* __restrict__ in, short* __restrict__ out, int S)
{
    __shared__ float t[64][65];
    const int s0 = blockIdx.x * 64;
    const int tid = threadIdx.x;
    {
        const int cpr = tid >> 2, ch = tid & 3;
        const float4* ip = (const float4*)(in + (size_t)cpr * S + s0 + ch * 16);
        #pragma unroll
        for (int i = 0; i < 4; ++i) {
            float4 v = ip[i]; int sb = ch * 16 + i * 4;
            t[sb][cpr] = v.x; t[sb + 1][cpr] = v.y; t[sb + 2][cpr] = v.z; t[sb + 3][cpr] = v.w;
        }
    }
    __syncthreads();
    {
        const int spr = tid >> 2, cc = (tid & 3) * 16;
        short8 o0, o1;
        #pragma unroll
        for (int q = 0; q < 8; ++q) { o0[q] = f2bf(t[spr][cc + q]); o1[q] = f2bf(t[spr][cc + 8 + q]); }
        short* op = out + (size_t)(s0 + spr) * 64 + cc;
        *(short8*)op = o0;
        *(short8*)(op + 8) = o1;
    }
}

// w OIDHW fp32 [o][ci][t] -> bf16 [t][o][ci]
__global__ __launch_bounds__(256)
void prep_w(const float* __restrict__ w, short* __restrict__ dst, int CIN, int KSZ)
{
    int i = blockIdx.x * 256 + threadIdx.x;
    int n = KSZ * 64 * CIN;
    if (i >= n) return;
    int t = i / (64 * CIN); int r = i % (64 * CIN); int o = r / CIN; int ci = r % CIN;
    dst[i] = f2bf(w[(size_t)(o * CIN + ci) * KSZ + t]);
}

__global__ void finalize_stats(const float* __restrict__ stats, const float* __restrict__ g,
                               const float* __restrict__ b, float invN, float* __restrict__ aff)
{
    int c = threadIdx.x;                    // 64 threads
    float m = stats[c] * invN;
    float var = stats[64 + c] * invN - m * m;
    float rstd = rsqrtf(var + BN_EPS);
    float sc = g[c] * rstd;
    aff[c] = sc;
    aff[64 + c] = b[c] - m * sc;
}

// in-place affine on the INTERIOR of a padded channels-last buffer (64 ch)
template<int MODE> // 1 = fine, 2 = coarse
__global__ __launch_bounds__(256)
void affine_pad(short* __restrict__ buf, const float* __restrict__ aff, int n8)
{
    int i = blockIdx.x * 256 + threadIdx.x;
    if (i >= n8) return;
    int s = i >> 3, cb = (i & 7) * 8;
    int p = (MODE == 1) ? pidx_fine(s) : pidx_coarse(s);
    short* ptr = buf + (size_t)p * 64 + cb;
    short8 v = *(const short8*)ptr;
    short8 o;
    #pragma unroll
    for (int q = 0; q < 8; ++q) {
        int c = cb + q;
        o[q] = f2bf(bf2f(v[q]) * aff[c] + aff[64 + c]);
    }
    *(short8*)ptr = o;
}

// final: E-raw compact [S][64] bf16 --aff3--> out NCDHW fp32
__global__ __launch_bounds__(256)
void final_out(const short* __restrict__ in, float* __restrict__ out, const float* __restrict__ aff)
{
    __shared__ float t[64][65];
    const int s0 = blockIdx.x * 64;
    const int tid = threadIdx.x;
    {
        const int spr = tid >> 2, ch = tid & 3;
        const short8* ip = (const short8*)(in + (size_t)(s0 + spr) * 64 + ch * 16);
        short8 v0 = ip[0], v1 = ip[1];
        #pragma unroll
        for (int q = 0; q < 8; ++q) { int c = ch * 16 + q;     t[spr][c] = bf2f(v0[q]) * aff[c] + aff[64 + c]; }
        #pragma unroll
        for (int q = 0; q < 8; ++q) { int c = ch * 16 + 8 + q; t[spr][c] = bf2f(v1[q]) * aff[c] + aff[64 + c]; }
    }
    __syncthreads();
    {
        const int c = tid >> 2, sc = (tid & 3) * 16;
        #pragma unroll
        for (int i = 0; i < 4; ++i) {
            float4 w;
            w.x = t[sc + 4 * i][c]; w.y = t[sc + 4 * i + 1][c];
            w.z = t[sc + 4 * i + 2][c]; w.w = t[sc + 4 * i + 3][c];
            *(float4*)(out + (size_t)c * DHW1 + s0 + sc + 4 * i) = w;
        }
    }
}

// ---------------------------------------------------------------------------
// Padded implicit-GEMM conv. Block 256 thr = 4 waves; wave owns 64 rows (4 mg frags).
// A: padded channels-last bf16 (trash plane = GD). Wt: [KSZ][64][CIN]. No predication.
// OUTMODE: 0 compact [S][64], 1 fine-padded, 2 coarse-padded.
template<int CIN, int KD, int KH, int KW, int PD, int PH, int PW,
         int GD, int GH, int GW, int OUTMODE, bool STATS>
__global__ __launch_bounds__(256, 2)
void convmm3(const short* __restrict__ A, const short* __restrict__ Wt,
             short* __restrict__ Out, float* __restrict__ stats)
{
    constexpr int PW_ = GW + 2;
    constexpr int PLPTS = (GH + 2) * PW_;
    constexpr int HWg = GH * GW;
    constexpr int KCN = CIN / 32;

    const int tid = threadIdx.x, lane = tid & 63, wave = tid >> 6;
    const int rl = lane & 15, kg = lane >> 4;
    const int row0 = blockIdx.x * 256;

    int zin[4][KD];
    #pragma unroll
    for (int mg = 0; mg < 4; ++mg) {
        int s = row0 + wave * 64 + mg * 16 + rl;
        int z = s / HWg; int r = s - z * HWg; int y = r / GW; int x = r - y * GW;
        int ib = ((y + 1) * PW_ + (x + 1)) * CIN + kg * 8;
        #pragma unroll
        for (int kd = 0; kd < KD; ++kd) {
            int iz = z + kd - PD;
            int pl = ((unsigned)iz < (unsigned)GD) ? iz : GD;   // trash plane = GD (zeros)
            zin[mg][kd] = pl * (PLPTS * CIN) + ib;
        }
    }
    const int boff = rl * CIN + kg * 8;

    f32x4 acc[4][4];
    #pragma unroll
    for (int mg = 0; mg < 4; ++mg)
        #pragma unroll
        for (int ng = 0; ng < 4; ++ng)
            acc[mg][ng] = (f32x4){0.f, 0.f, 0.f, 0.f};

    #pragma unroll
    for (int kd = 0; kd < KD; ++kd)
    #pragma unroll
    for (int kh = 0; kh < KH; ++kh)
    #pragma unroll
    for (int kw = 0; kw < KW; ++kw) {
        const int t = (kd * KH + kh) * KW + kw;
        const int dlt = ((kh - PH) * PW_ + (kw - PW)) * CIN;
        int ao[4];
        #pragma unroll
        for (int mg = 0; mg < 4; ++mg) ao[mg] = zin[mg][kd] + dlt;
        #pragma unroll
        for (int kc = 0; kc < KCN; ++kc) {
            short8 av[4], bv[4];
            #pragma unroll
            for (int mg = 0; mg < 4; ++mg)
                av[mg] = *(const short8*)(A + ao[mg] + kc * 32);
            #pragma unroll
            for (int ng = 0; ng < 4; ++ng)
                bv[ng] = *(const short8*)(Wt + (t * 64 + ng * 16) * CIN + boff + kc * 32);
            #pragma unroll
            for (int mg = 0; mg < 4; ++mg)
                #pragma unroll
                for (int ng = 0; ng < 4; ++ng)
                    acc[mg][ng] = __builtin_amdgcn_mfma_f32_16x16x32_bf16(av[mg], bv[ng], acc[mg][ng], 0, 0, 0);
        }
    }

    __shared__ short tile[256][72];
    __shared__ float red[2][4][64];

    #pragma unroll
    for (int mg = 0; mg < 4; ++mg)
        #pragma unroll
        for (int ng = 0; ng < 4; ++ng)
            #pragma unroll
            for (int j = 0; j < 4; ++j) {
                float v = acc[mg][ng][j];
                if (STATS) v = (v >= 0.f) ? v : SLOPE * v;
                tile[wave * 64 + mg * 16 + kg * 4 + j][ng * 16 + rl] = f2bf(v);
            }
    __syncthreads();

    #pragma unroll
    for (int i = 0; i < 8; ++i) {
        int chunk = i * 256 + tid;            // 2048 chunks of 8 shorts
        int r = chunk >> 3, cc = (chunk & 7) * 8;
        int s = row0 + r;
        size_t o;
        if (OUTMODE == 0)      o = (size_t)s * 64 + cc;
        else if (OUTMODE == 1) o = (size_t)pidx_fine(s) * 64 + cc;
        else                   o = (size_t)pidx_coarse(s) * 64 + cc;
        *(short8*)(Out + o) = *(const short8*)&tile[r][cc];
    }

    if (STATS) {
        float s1 = 0.f, s2 = 0.f;
        const int col = tid & 63, rg = tid >> 6;
        #pragma unroll 4
        for (int r = rg * 64; r < rg * 64 + 64; ++r) {
            float v = bf2f(tile[r][col]); s1 += v; s2 += v * v;
        }
        red[0][rg][col] = s1; red[1][rg][col] = s2;
        __syncthreads();
        if (tid < 64) {
            float a = red[0][0][tid] + red[0][1][tid] + red[0][2][tid] + red[0][3][tid];
            float b = red[1][0][tid] + red[1][1][tid] + red[1][2][tid] + red[1][3][tid];
            atomicAdd(&stats[tid], a);
            atomicAdd(&stats[64 + tid], b);
        }
    }
}

// ---------------------------------------------------------------------------
// Transposed conv by output-parity class. grid (144, 8): blockIdx.y = pz*4+py*2+px.
// Reads Y0pad (coarse padded, 64ch), adds compact skip, writes fine-padded Out.
__global__ __launch_bounds__(256, 2)
void tconv_cls(const short* __restrict__ Y, const short* __restrict__ Wt,
               const short* __restrict__ SK, short* __restrict__ Out)
{
    const int cls = blockIdx.y;
    const int pz = (cls >> 2) & 1, py = (cls >> 1) & 1, px = cls & 1;
    const int tid = threadIdx.x, lane = tid & 63, wave = tid >> 6;
    const int rl = lane & 15, kg = lane >> 4;
    const int row0 = blockIdx.x * 256;

    int zin0[4], zin1[4];
    #pragma unroll
    for (int mg = 0; mg < 4; ++mg) {
        int s = row0 + wave * 64 + mg * 16 + rl;     // class-local, coarse geometry
        int zc = s / HW0; int r = s - zc * HW0; int yc = r / W0; int xc = r - yc * W0;
        int ib = ((yc + 1) * 50 + (xc + 1)) * 64 + kg * 8;
        int iz0 = zc;                 // always valid (0..15)
        int iz1 = zc + 1;             // may be 16 -> trash
        zin0[mg] = iz0 * (CP_PLPTS * 64) + ib;
        zin1[mg] = ((iz1 < 16) ? iz1 : 16) * (CP_PLPTS * 64) + ib;
    }
    const int boff = rl * 64 + kg * 8;

    f32x4 acc[4][4];
    #pragma unroll
    for (int mg = 0; mg < 4; ++mg)
        #pragma unroll
        for (int ng = 0; ng < 4; ++ng)
            acc[mg][ng] = (f32x4){0.f, 0.f, 0.f, 0.f};

    for (int a = 0; a <= pz; ++a) {
        const int kd = pz ? 2 * a : 1;
        for (int b = 0; b <= py; ++b) {
            const int kh = py ? 2 * b : 1;
            for (int c = 0; c <= px; ++c) {
                const int kw = px ? 2 * c : 1;
                const int t = kd * 9 + kh * 3 + kw;
                const int dlt = (b * 50 + c) * 64;
                int ao[4];
                #pragma unroll
                for (int mg = 0; mg < 4; ++mg)
                    ao[mg] = (a ? zin1[mg] : zin0[mg]) + dlt;
                #pragma unroll
                for (int kc = 0; kc < 2; ++kc) {
                    short8 av[4], bv[4];
                    #pragma unroll
                    for (int mg = 0; mg < 4; ++mg)
                        av[mg] = *(const short8*)(Y + ao[mg] + kc * 32);
                    #pragma unroll
                    for (int ng = 0; ng < 4; ++ng)
                        bv[ng] = *(const short8*)(Wt + (t * 64 + ng * 16) * 64 + boff + kc * 32);
                    #pragma unroll
                    for (int mg = 0; mg < 4; ++mg)
                        #pragma unroll
                        for (int ng = 0; ng < 4; ++ng)
                            acc[mg][ng] = __builtin_amdgcn_mfma_f32_16x16x32_bf16(av[mg], bv[ng], acc[mg][ng], 0, 0, 0);
                }
            }
        }
    }

    __shared__ short tile[256][72];
    #pragma unroll
    for (int mg = 0; mg < 4; ++mg)
        #pragma unroll
        for (int ng = 0; ng < 4; ++ng)
            #pragma unroll
            for (int j = 0; j < 4; ++j)
                tile[wave * 64 + mg * 16 + kg * 4 + j][ng * 16 + rl] = f2bf(acc[mg][ng][j]);
    __syncthreads();

    #pragma unroll
    for (int i = 0; i < 8; ++i) {
        int chunk = i * 256 + tid;
        int r = chunk >> 3, cc = (chunk & 7) * 8;
        int sl = row0 + r;
        int zc = sl / HW0; int rr = sl - zc * HW0; int yc = rr / W0; int xc = rr - yc * W0;
        int z = 2 * zc + pz, y = 2 * yc + py, x = 2 * xc + px;
        size_t so = (size_t)((z * H1 + y) * W1_ + x) * 64 + cc;          // compact (skip)
        size_t po = (size_t)(z * FP_PLPTS + (y + 1) * 98 + (x + 1)) * 64 + cc;
        short8 v = *(const short8*)&tile[r][cc];
        short8 skv = *(const short8*)(SK + so);
        short8 o;
        #pragma unroll
        for (int q = 0; q < 8; ++q) o[q] = f2bf(bf2f(v[q]) + bf2f(skv[q]));
        *(short8*)(Out + po) = o;
    }
}

// ---------------------------------------------------------------------------
extern "C" void kernel_launch(void* const* d_in, const int* in_sizes, int n_in,
                              void* d_out, int out_size, void* d_ws, size_t ws_size,
                              hipStream_t stream)
{
    const float* x       = (const float*)d_in[0];
    const float* skip    = (const float*)d_in[1];
    const float* w_trans = (const float*)d_in[2];
    const float* g_t     = (const float*)d_in[3];
    const float* b_t     = (const float*)d_in[4];
    const float* w_up    = (const float*)d_in[5];
    const float* w1      = (const float*)d_in[6];
    const float* g1      = (const float*)d_in[7];
    const float* b1      = (const float*)d_in[8];
    const float* w2      = (const float*)d_in[9];
    const float* g2      = (const float*)d_in[10];
    const float* b2      = (const float*)d_in[11];
    const float* w3      = (const float*)d_in[12];
    const float* g3      = (const float*)d_in[13];
    const float* b3      = (const float*)d_in[14];
    float* out = (float*)d_out;

    // ws: PadA | PadB | stats/affs      (total 81,138,688 B <= proven ws_size)
    char* ws = (char*)d_ws;
    short* PadA = (short*)ws;
    short* PadB = (short*)(ws + (size_t)FP_ELEMS * 2);
    float* stats = (float*)(ws + (size_t)FP_ELEMS * 4);
    float* affs  = stats + 512;

    float* st0 = stats;       float* af0 = affs;
    float* st1 = stats + 128; float* af1 = affs + 128;
    float* st2 = stats + 256; float* af2 = affs + 256;
    float* st3 = stats + 384; float* af3 = affs + 384;

    // d_out scratch: X0pad | Y0pad | SKb | weights   (all dead before final_out writes)
    char* ob = (char*)d_out;
    short* X0  = (short*)ob;                       // 10,880,000 B
    short* Y0  = (short*)(ob + 10880000);          //  5,440,000 B
    short* SKb = (short*)(ob + 16320000);          // 37,748,736 B
    short* wt_t  = (short*)(ob + 54068736);        // 27*64*128 elems
    short* wt_up = wt_t + 221184;                  // 27*64*64
    short* wt_1  = wt_up + 110592;                 // 9*64*64
    short* wt_2  = wt_1 + 36864;
    short* wt_3  = wt_2 + 36864;

    // zero padded buffers (halos + trash planes) and stats — every call (graph replay)
    hipMemsetAsync(ws, 0, (size_t)FP_ELEMS * 4, stream);
    hipMemsetAsync(stats, 0, 4096, stream);
    hipMemsetAsync(d_out, 0, 16320000, stream);

    // weight repacks
    prep_w<<<(27 * 64 * 128 + 255) / 256, 256, 0, stream>>>(w_trans, wt_t, 128, 27);
    prep_w<<<(27 * 64 * 64 + 255) / 256, 256, 0, stream>>>(w_up, wt_up, 64, 27);
    prep_w<<<(9 * 64 * 64 + 255) / 256, 256, 0, stream>>>(w1, wt_1, 64, 9);
    prep_w<<<(9 * 64 * 64 + 255) / 256, 256, 0, stream>>>(w2, wt_2, 64, 9);
    prep_w<<<(27 * 64 * 64 + 255) / 256, 256, 0, stream>>>(w3, wt_3, 64, 27);

    // input transposes
    to_cl_pad128<<<dim3(DHW0 / 64, 2), 256, 0, stream>>>(x, X0);
    to_cl_bf16<<<DHW1 / 64, 256, 0, stream>>>(skip, SKb, DHW1);

    // stage A: subm 3x3x3 CIN=128 on coarse grid -> Y0pad (raw lrelu) + stats
    convmm3<128, 3, 3, 3, 1, 1, 1, 16, 48, 48, 2, true>
        <<<DHW0 / 256, 256, 0, stream>>>(X0, wt_t, Y0, st0);
    finalize_stats<<<1, 64, 0, stream>>>(st0, g_t, b_t, 1.f / DHW0, af0);
    affine_pad<2><<<(DHW0 * 8 + 255) / 256, 256, 0, stream>>>(Y0, af0, DHW0 * 8);

    // stage B: transposed conv by parity class + skip -> PadA
    tconv_cls<<<dim3(DHW0 / 256, 8), 256, 0, stream>>>(Y0, wt_up, SKb, PadA);

    // stage C: conv (1,3,3) pad (0,1,1) -> PadB + stats
    convmm3<64, 1, 3, 3, 0, 1, 1, 32, 96, 96, 1, true>
        <<<DHW1 / 256, 256, 0, stream>>>(PadA, wt_1, PadB, st1);
    finalize_stats<<<1, 64, 0, stream>>>(st1, g1, b1, 1.f / DHW1, af1);
    affine_pad<1><<<(DHW1 * 8 + 255) / 256, 256, 0, stream>>>(PadB, af1, DHW1 * 8);

    // stage D: conv (3,1,3) pad (1,0,1) -> PadA + stats
    convmm3<64, 3, 1, 3, 1, 0, 1, 32, 96, 96, 1, true>
        <<<DHW1 / 256, 256, 0, stream>>>(PadB, wt_2, PadA, st2);
    finalize_stats<<<1, 64, 0, stream>>>(st2, g2, b2, 1.f / DHW1, af2);
    affine_pad<1><<<(DHW1 * 8 + 255) / 256, 256, 0, stream>>>(PadA, af2, DHW1 * 8);

    // stage E: conv (3,3,3) pad 1 -> PadB as COMPACT raw + stats
    convmm3<64, 3, 3, 3, 1, 1, 1, 32, 96, 96, 0, true>
        <<<DHW1 / 256, 256, 0, stream>>>(PadA, wt_3, PadB, st3);
    finalize_stats<<<1, 64, 0, stream>>>(st3, g3, b3, 1.f / DHW1, af3);

    // final: aff3 + transpose to NCDHW fp32
    final_out<<<DHW1 / 64, 256, 0, stream>>>(PadB, out, af3);
}

// Round 4
// 498.446 us; speedup vs baseline: 73.0830x; 1.4230x over previous
//
#include <hip/hip_runtime.h>

#define SLOPE 0.01f
#define BN_EPS 1e-5f

typedef __attribute__((ext_vector_type(8))) short short8;
typedef __attribute__((ext_vector_type(4))) float f32x4;

static constexpr int D1 = 32, H1 = 96, W1_ = 96;
static constexpr int HW1 = H1 * W1_, DHW1 = D1 * HW1;        // 294912
static constexpr int D0 = 16, H0 = 48, W0 = 48;
static constexpr int HW0 = H0 * W0, DHW0 = D0 * HW0;         // 36864

// padded geometries (y/x halo of 1, plus one trailing all-zero "trash" z-plane)
static constexpr int FP_PLPTS = 98 * 98;            // fine padded plane pts
static constexpr int CP_PLPTS = 50 * 50;            // coarse padded plane pts
static constexpr int FP_ELEMS = 33 * FP_PLPTS * 64; // fine padded buffer elems

__device__ __forceinline__ short f2bf(float f) {
    unsigned u = __builtin_bit_cast(unsigned, f);
    unsigned r = (u + 0x7fffu + ((u >> 16) & 1u)) >> 16;
    return (short)r;
}
__device__ __forceinline__ float bf2f(short s) {
    unsigned u = ((unsigned)(unsigned short)s) << 16;
    return __builtin_bit_cast(float, u);
}
__device__ __forceinline__ int pidx_fine(int s) {
    int z = s / HW1; int r = s - z * HW1; int y = r / W1_; int x = r - y * W1_;
    return z * FP_PLPTS + (y + 1) * 98 + (x + 1);
}
__device__ __forceinline__ int pidx_coarse(int s) {
    int z = s / HW0; int r = s - z * HW0; int y = r / W0; int x = r - y * W0;
    return z * CP_PLPTS + (y + 1) * 50 + (x + 1);
}
__device__ __forceinline__ void gload16(const void* g, void* l) {
    __builtin_amdgcn_global_load_lds(
        (const __attribute__((address_space(1))) void*)g,
        (__attribute__((address_space(3))) void*)l, 16, 0, 0);
}

// ---------------------------------------------------------------------------
__global__ __launch_bounds__(256)
void to_cl_pad128(const float* __restrict__ in, short* __restrict__ out)
{
    __shared__ float t[64][65];
    const int s0 = blockIdx.x * 64, c0 = blockIdx.y * 64;
    const int tid = threadIdx.x;
    {
        const int cpr = tid >> 2, ch = tid & 3;
        const float4* ip = (const float4*)(in + (size_t)(c0 + cpr) * DHW0 + s0 + ch * 16);
        #pragma unroll
        for (int i = 0; i < 4; ++i) {
            float4 v = ip[i]; int sb = ch * 16 + i * 4;
            t[sb][cpr] = v.x; t[sb + 1][cpr] = v.y; t[sb + 2][cpr] = v.z; t[sb + 3][cpr] = v.w;
        }
    }
    __syncthreads();
    {
        const int spr = tid >> 2, cc = (tid & 3) * 16;
        short8 o0, o1;
        #pragma unroll
        for (int q = 0; q < 8; ++q) { o0[q] = f2bf(t[spr][cc + q]); o1[q] = f2bf(t[spr][cc + 8 + q]); }
        const int p = pidx_coarse(s0 + spr);
        short* op = out + (size_t)p * 128 + c0 + cc;
        *(short8*)op = o0;
        *(short8*)(op + 8) = o1;
    }
}

__global__ __launch_bounds__(256)
void to_cl_bf16(const float* __restrict__ in, short* __restrict__ out, int S)
{
    __shared__ float t[64][65];
    const int s0 = blockIdx.x * 64;
    const int tid = threadIdx.x;
    {
        const int cpr = tid >> 2, ch = tid & 3;
        const float4* ip = (const float4*)(in + (size_t)cpr * S + s0 + ch * 16);
        #pragma unroll
        for (int i = 0; i < 4; ++i) {
            float4 v = ip[i]; int sb = ch * 16 + i * 4;
            t[sb][cpr] = v.x; t[sb + 1][cpr] = v.y; t[sb + 2][cpr] = v.z; t[sb + 3][cpr] = v.w;
        }
    }
    __syncthreads();
    {
        const int spr = tid >> 2, cc = (tid & 3) * 16;
        short8 o0, o1;
        #pragma unroll
        for (int q = 0; q < 8; ++q) { o0[q] = f2bf(t[spr][cc + q]); o1[q] = f2bf(t[spr][cc + 8 + q]); }
        short* op = out + (size_t)(s0 + spr) * 64 + cc;
        *(short8*)op = o0;
        *(short8*)(op + 8) = o1;
    }
}

__global__ __launch_bounds__(256)
void prep_w(const float* __restrict__ w, short* __restrict__ dst, int CIN, int KSZ)
{
    int i = blockIdx.x * 256 + threadIdx.x;
    int n = KSZ * 64 * CIN;
    if (i >= n) return;
    int t = i / (64 * CIN); int r = i % (64 * CIN); int o = r / CIN; int ci = r % CIN;
    dst[i] = f2bf(w[(size_t)(o * CIN + ci) * KSZ + t]);
}

__global__ void finalize_stats(const float* __restrict__ stats, const float* __restrict__ g,
                               const float* __restrict__ b, float invN, float* __restrict__ aff)
{
    int c = threadIdx.x;
    float m = stats[c] * invN;
    float var = stats[64 + c] * invN - m * m;
    float rstd = rsqrtf(var + BN_EPS);
    float sc = g[c] * rstd;
    aff[c] = sc;
    aff[64 + c] = b[c] - m * sc;
}

template<int MODE> // 1 = fine, 2 = coarse
__global__ __launch_bounds__(256)
void affine_pad(short* __restrict__ buf, const float* __restrict__ aff, int n8)
{
    int i = blockIdx.x * 256 + threadIdx.x;
    if (i >= n8) return;
    int s = i >> 3, cb = (i & 7) * 8;
    int p = (MODE == 1) ? pidx_fine(s) : pidx_coarse(s);
    short* ptr = buf + (size_t)p * 64 + cb;
    short8 v = *(const short8*)ptr;
    short8 o;
    #pragma unroll
    for (int q = 0; q < 8; ++q) {
        int c = cb + q;
        o[q] = f2bf(bf2f(v[q]) * aff[c] + aff[64 + c]);
    }
    *(short8*)ptr = o;
}

__global__ __launch_bounds__(256)
void final_out(const short* __restrict__ in, float* __restrict__ out, const float* __restrict__ aff)
{
    __shared__ float t[64][65];
    const int s0 = blockIdx.x * 64;
    const int tid = threadIdx.x;
    {
        const int spr = tid >> 2, ch = tid & 3;
        const short8* ip = (const short8*)(in + (size_t)(s0 + spr) * 64 + ch * 16);
        short8 v0 = ip[0], v1 = ip[1];
        #pragma unroll
        for (int q = 0; q < 8; ++q) { int c = ch * 16 + q;     t[spr][c] = bf2f(v0[q]) * aff[c] + aff[64 + c]; }
        #pragma unroll
        for (int q = 0; q < 8; ++q) { int c = ch * 16 + 8 + q; t[spr][c] = bf2f(v1[q]) * aff[c] + aff[64 + c]; }
    }
    __syncthreads();
    {
        const int c = tid >> 2, sc = (tid & 3) * 16;
        #pragma unroll
        for (int i = 0; i < 4; ++i) {
            float4 w;
            w.x = t[sc + 4 * i][c]; w.y = t[sc + 4 * i + 1][c];
            w.z = t[sc + 4 * i + 2][c]; w.w = t[sc + 4 * i + 3][c];
            *(float4*)(out + (size_t)c * DHW1 + s0 + sc + 4 * i) = w;
        }
    }
}

// ---------------------------------------------------------------------------
// 2-phase LDS-staged implicit-GEMM conv (T3 minimum recipe, T2 swizzle).
// Block = 256 thr = 4 waves. Wave owns 16*MG rows. MR = 64*MG rows per block.
// A: padded channels-last bf16 (trash z-plane = GD, zeros). Wt: [KSZ][64][CIN].
// LDS: As[2][MR][CIN] + Bs[2][64][CIN], XOR-swizzled chunks (chunk^=(row&7)),
// swizzle applied on the per-lane GLOBAL SOURCE at stage and on ds_read (rule 21).
template<int MG, int CIN, int KD, int KH, int KW, int PD, int PH, int PW,
         int GD, int GH, int GW, int OUTMODE, bool STATS>
__global__ __launch_bounds__(256, 2)
void convmm4(const short* __restrict__ A, const short* __restrict__ Wt,
             short* __restrict__ Out, float* __restrict__ stats)
{
    constexpr int MR   = 64 * MG;
    constexpr int KSZ  = KD * KH * KW;
    constexpr int PPW  = GW + 2;
    constexpr int PLP  = (GH + 2) * PPW;
    constexpr int HWg  = GH * GW;
    constexpr int CPR  = CIN / 8;                // 16B chunks per row
    constexpr int L2C  = (CIN == 64) ? 3 : 4;
    constexpr int RPI  = 64 / CPR;               // rows per 1KB gload instr
    constexpr int ASZ  = MR * CIN * 2;           // bytes per A buffer
    constexpr int BSZ  = 64 * CIN * 2;
    constexpr int API  = ASZ / 4096;             // gload instrs per wave (A)
    constexpr int BPI  = BSZ / 4096;
    constexpr int KCN  = CIN / 32;

    __shared__ char smem[2 * ASZ + 2 * BSZ];

    const int tid = threadIdx.x, lane = tid & 63, wave = tid >> 6;
    const int rl = lane & 15, kg = lane >> 4;

    // XCD-aware bijective swizzle (all grids are multiples of 8)
    const int nwg = gridDim.x;
    const int bid = blockIdx.x;
    const int bswz = (nwg & 7) ? bid : ((bid & 7) * (nwg >> 3) + (bid >> 3));
    const int row0 = bswz * MR;

    // per-thread staging precompute
    int zA[API], yxA[API], cofA[API];
    #pragma unroll
    for (int i = 0; i < API; ++i) {
        const int gi = wave * API + i;
        const int r = gi * RPI + (lane >> L2C);
        const int s = row0 + r;
        const int z = s / HWg; const int rm = s - z * HWg;
        const int y = rm / GW; const int x = rm - y * GW;
        zA[i] = z;
        yxA[i] = (y + 1) * PPW + (x + 1);
        cofA[i] = ((lane & (CPR - 1)) ^ (r & 7)) * 8;
    }
    int rB[BPI], cofB[BPI];
    #pragma unroll
    for (int i = 0; i < BPI; ++i) {
        const int gi = wave * BPI + i;
        const int r = gi * RPI + (lane >> L2C);
        rB[i] = r;
        cofB[i] = ((lane & (CPR - 1)) ^ (r & 7)) * 8;
    }

    auto stageA = [&](int bsel, int kd, int kh, int kw) {
        const int dyx = (kh - PH) * PPW + (kw - PW);
        #pragma unroll
        for (int i = 0; i < API; ++i) {
            int zp = zA[i] + (kd - PD);
            int pl = ((unsigned)zp < (unsigned)GD) ? zp : GD;     // trash plane (zeros)
            const short* src = A + ((size_t)pl * PLP + yxA[i] + dyx) * CIN + cofA[i];
            void* dst = smem + bsel * ASZ + (wave * API + i) * 1024;
            gload16(src, dst);
        }
    };
    auto stageB = [&](int bsel, int t) {
        const short* wt = Wt + (size_t)t * 64 * CIN;
        #pragma unroll
        for (int i = 0; i < BPI; ++i) {
            const short* src = wt + rB[i] * CIN + cofB[i];
            void* dst = smem + 2 * ASZ + bsel * BSZ + (wave * BPI + i) * 1024;
            gload16(src, dst);
        }
    };

    f32x4 acc[MG][4];
    #pragma unroll
    for (int mg = 0; mg < MG; ++mg)
        #pragma unroll
        for (int ng = 0; ng < 4; ++ng)
            acc[mg][ng] = (f32x4){0.f, 0.f, 0.f, 0.f};

    auto comp = [&](int bsel) {
        const short* ab = (const short*)(smem + bsel * ASZ);
        const short* bb = (const short*)(smem + 2 * ASZ + bsel * BSZ);
        #pragma unroll
        for (int kc = 0; kc < KCN; ++kc) {
            short8 av[MG], bv[4];
            #pragma unroll
            for (int mg = 0; mg < MG; ++mg) {
                const int r = wave * (16 * MG) + mg * 16 + rl;
                const int c = (kc * 4 + kg) ^ (r & 7);
                av[mg] = *(const short8*)(ab + r * CIN + c * 8);
            }
            #pragma unroll
            for (int ng = 0; ng < 4; ++ng) {
                const int r = ng * 16 + rl;
                const int c = (kc * 4 + kg) ^ (r & 7);
                bv[ng] = *(const short8*)(bb + r * CIN + c * 8);
            }
            #pragma unroll
            for (int mg = 0; mg < MG; ++mg)
                #pragma unroll
                for (int ng = 0; ng < 4; ++ng)
                    acc[mg][ng] = __builtin_amdgcn_mfma_f32_16x16x32_bf16(av[mg], bv[ng], acc[mg][ng], 0, 0, 0);
        }
    };

    // prologue
    stageA(0, 0, 0, 0);
    stageB(0, 0);
    __syncthreads();

    #pragma unroll
    for (int t = 0; t < KSZ; ++t) {
        const int cur = t & 1;
        if (t + 1 < KSZ) {
            const int t1 = t + 1;
            const int kd = t1 / (KH * KW), rm = t1 % (KH * KW);
            stageA(cur ^ 1, kd, rm / KW, rm % KW);
            stageB(cur ^ 1, t1);
        }
        comp(cur);
        __syncthreads();
    }

    // epilogue: tile aliases As[0]; red aliases Bs
    short (*tile)[64] = (short(*)[64])smem;
    float* red = (float*)(smem + 2 * ASZ);

    #pragma unroll
    for (int mg = 0; mg < MG; ++mg)
        #pragma unroll
        for (int ng = 0; ng < 4; ++ng)
            #pragma unroll
            for (int j = 0; j < 4; ++j) {
                float v = acc[mg][ng][j];
                if (STATS) v = (v >= 0.f) ? v : SLOPE * v;
                tile[wave * (16 * MG) + mg * 16 + kg * 4 + j][ng * 16 + rl] = f2bf(v);
            }
    __syncthreads();

    #pragma unroll
    for (int i = 0; i < MR / 32; ++i) {
        const int chunk = i * 256 + tid;
        const int r = chunk >> 3, cc = (chunk & 7) * 8;
        const int s = row0 + r;
        size_t o;
        if (OUTMODE == 0)      o = (size_t)s * 64 + cc;
        else if (OUTMODE == 1) o = (size_t)pidx_fine(s) * 64 + cc;
        else                   o = (size_t)pidx_coarse(s) * 64 + cc;
        *(short8*)(Out + o) = *(const short8*)&tile[r][cc];
    }

    if (STATS) {
        float s1 = 0.f, s2 = 0.f;
        const int col = tid & 63, rg = tid >> 6;
        #pragma unroll 4
        for (int r = rg * (MR / 4); r < (rg + 1) * (MR / 4); ++r) {
            float v = bf2f(tile[r][col]); s1 += v; s2 += v * v;
        }
        red[(0 * 4 + rg) * 64 + col] = s1;
        red[(1 * 4 + rg) * 64 + col] = s2;
        __syncthreads();
        if (tid < 64) {
            float a = red[0 * 256 + 0 * 64 + tid] + red[0 * 256 + 1 * 64 + tid] +
                      red[0 * 256 + 2 * 64 + tid] + red[0 * 256 + 3 * 64 + tid];
            float b = red[1 * 256 + 0 * 64 + tid] + red[1 * 256 + 1 * 64 + tid] +
                      red[1 * 256 + 2 * 64 + tid] + red[1 * 256 + 3 * 64 + tid];
            atomicAdd(&stats[tid], a);
            atomicAdd(&stats[64 + tid], b);
        }
    }
}

// ---------------------------------------------------------------------------
// Transposed conv by output-parity class (unchanged from round 3).
__global__ __launch_bounds__(256, 2)
void tconv_cls(const short* __restrict__ Y, const short* __restrict__ Wt,
               const short* __restrict__ SK, short* __restrict__ Out)
{
    const int cls = blockIdx.y;
    const int pz = (cls >> 2) & 1, py = (cls >> 1) & 1, px = cls & 1;
    const int tid = threadIdx.x, lane = tid & 63, wave = tid >> 6;
    const int rl = lane & 15, kg = lane >> 4;
    const int row0 = blockIdx.x * 256;

    int zin0[4], zin1[4];
    #pragma unroll
    for (int mg = 0; mg < 4; ++mg) {
        int s = row0 + wave * 64 + mg * 16 + rl;
        int zc = s / HW0; int r = s - zc * HW0; int yc = r / W0; int xc = r - yc * W0;
        int ib = ((yc + 1) * 50 + (xc + 1)) * 64 + kg * 8;
        zin0[mg] = zc * (CP_PLPTS * 64) + ib;
        zin1[mg] = ((zc + 1 < 16) ? zc + 1 : 16) * (CP_PLPTS * 64) + ib;
    }
    const int boff = rl * 64 + kg * 8;

    f32x4 acc[4][4];
    #pragma unroll
    for (int mg = 0; mg < 4; ++mg)
        #pragma unroll
        for (int ng = 0; ng < 4; ++ng)
            acc[mg][ng] = (f32x4){0.f, 0.f, 0.f, 0.f};

    for (int a = 0; a <= pz; ++a) {
        const int kd = pz ? 2 * a : 1;
        for (int b = 0; b <= py; ++b) {
            const int kh = py ? 2 * b : 1;
            for (int c = 0; c <= px; ++c) {
                const int kw = px ? 2 * c : 1;
                const int t = kd * 9 + kh * 3 + kw;
                const int dlt = (b * 50 + c) * 64;
                int ao[4];
                #pragma unroll
                for (int mg = 0; mg < 4; ++mg)
                    ao[mg] = (a ? zin1[mg] : zin0[mg]) + dlt;
                #pragma unroll
                for (int kc = 0; kc < 2; ++kc) {
                    short8 av[4], bv[4];
                    #pragma unroll
                    for (int mg = 0; mg < 4; ++mg)
                        av[mg] = *(const short8*)(Y + ao[mg] + kc * 32);
                    #pragma unroll
                    for (int ng = 0; ng < 4; ++ng)
                        bv[ng] = *(const short8*)(Wt + (t * 64 + ng * 16) * 64 + boff + kc * 32);
                    #pragma unroll
                    for (int mg = 0; mg < 4; ++mg)
                        #pragma unroll
                        for (int ng = 0; ng < 4; ++ng)
                            acc[mg][ng] = __builtin_amdgcn_mfma_f32_16x16x32_bf16(av[mg], bv[ng], acc[mg][ng], 0, 0, 0);
                }
            }
        }
    }

    __shared__ short tile[256][72];
    #pragma unroll
    for (int mg = 0; mg < 4; ++mg)
        #pragma unroll
        for (int ng = 0; ng < 4; ++ng)
            #pragma unroll
            for (int j = 0; j < 4; ++j)
                tile[wave * 64 + mg * 16 + kg * 4 + j][ng * 16 + rl] = f2bf(acc[mg][ng][j]);
    __syncthreads();

    #pragma unroll
    for (int i = 0; i < 8; ++i) {
        int chunk = i * 256 + tid;
        int r = chunk >> 3, cc = (chunk & 7) * 8;
        int sl = row0 + r;
        int zc = sl / HW0; int rr = sl - zc * HW0; int yc = rr / W0; int xc = rr - yc * W0;
        int z = 2 * zc + pz, y = 2 * yc + py, x = 2 * xc + px;
        size_t so = (size_t)((z * H1 + y) * W1_ + x) * 64 + cc;
        size_t po = (size_t)(z * FP_PLPTS + (y + 1) * 98 + (x + 1)) * 64 + cc;
        short8 v = *(const short8*)&tile[r][cc];
        short8 skv = *(const short8*)(SK + so);
        short8 o;
        #pragma unroll
        for (int q = 0; q < 8; ++q) o[q] = f2bf(bf2f(v[q]) + bf2f(skv[q]));
        *(short8*)(Out + po) = o;
    }
}

// ---------------------------------------------------------------------------
extern "C" void kernel_launch(void* const* d_in, const int* in_sizes, int n_in,
                              void* d_out, int out_size, void* d_ws, size_t ws_size,
                              hipStream_t stream)
{
    const float* x       = (const float*)d_in[0];
    const float* skip    = (const float*)d_in[1];
    const float* w_trans = (const float*)d_in[2];
    const float* g_t     = (const float*)d_in[3];
    const float* b_t     = (const float*)d_in[4];
    const float* w_up    = (const float*)d_in[5];
    const float* w1      = (const float*)d_in[6];
    const float* g1      = (const float*)d_in[7];
    const float* b1      = (const float*)d_in[8];
    const float* w2      = (const float*)d_in[9];
    const float* g2      = (const float*)d_in[10];
    const float* b2      = (const float*)d_in[11];
    const float* w3      = (const float*)d_in[12];
    const float* g3      = (const float*)d_in[13];
    const float* b3      = (const float*)d_in[14];
    float* out = (float*)d_out;

    char* ws = (char*)d_ws;
    short* PadA = (short*)ws;
    short* PadB = (short*)(ws + (size_t)FP_ELEMS * 2);
    float* stats = (float*)(ws + (size_t)FP_ELEMS * 4);
    float* affs  = stats + 512;

    float* st0 = stats;       float* af0 = affs;
    float* st1 = stats + 128; float* af1 = affs + 128;
    float* st2 = stats + 256; float* af2 = affs + 256;
    float* st3 = stats + 384; float* af3 = affs + 384;

    char* ob = (char*)d_out;
    short* X0  = (short*)ob;                       // 10,880,000 B
    short* Y0  = (short*)(ob + 10880000);          //  5,440,000 B
    short* SKb = (short*)(ob + 16320000);          // 37,748,736 B
    short* wt_t  = (short*)(ob + 54068736);
    short* wt_up = wt_t + 221184;
    short* wt_1  = wt_up + 110592;
    short* wt_2  = wt_1 + 36864;
    short* wt_3  = wt_2 + 36864;

    hipMemsetAsync(ws, 0, (size_t)FP_ELEMS * 4, stream);
    hipMemsetAsync(stats, 0, 4096, stream);
    hipMemsetAsync(d_out, 0, 16320000, stream);

    prep_w<<<(27 * 64 * 128 + 255) / 256, 256, 0, stream>>>(w_trans, wt_t, 128, 27);
    prep_w<<<(27 * 64 * 64 + 255) / 256, 256, 0, stream>>>(w_up, wt_up, 64, 27);
    prep_w<<<(9 * 64 * 64 + 255) / 256, 256, 0, stream>>>(w1, wt_1, 64, 9);
    prep_w<<<(9 * 64 * 64 + 255) / 256, 256, 0, stream>>>(w2, wt_2, 64, 9);
    prep_w<<<(27 * 64 * 64 + 255) / 256, 256, 0, stream>>>(w3, wt_3, 64, 27);

    to_cl_pad128<<<dim3(DHW0 / 64, 2), 256, 0, stream>>>(x, X0);
    to_cl_bf16<<<DHW1 / 64, 256, 0, stream>>>(skip, SKb, DHW1);

    // stage A: subm 3x3x3 CIN=128 coarse -> Y0pad (raw lrelu) + stats   [MG=1, 576 blocks]
    convmm4<1, 128, 3, 3, 3, 1, 1, 1, 16, 48, 48, 2, true>
        <<<DHW0 / 64, 256, 0, stream>>>(X0, wt_t, Y0, st0);
    finalize_stats<<<1, 64, 0, stream>>>(st0, g_t, b_t, 1.f / DHW0, af0);
    affine_pad<2><<<(DHW0 * 8 + 255) / 256, 256, 0, stream>>>(Y0, af0, DHW0 * 8);

    // stage B: transposed conv by parity class + skip -> PadA
    tconv_cls<<<dim3(DHW0 / 256, 8), 256, 0, stream>>>(Y0, wt_up, SKb, PadA);

    // stage C: conv (1,3,3) pad (0,1,1) -> PadB + stats   [MG=4, 1152 blocks]
    convmm4<4, 64, 1, 3, 3, 0, 1, 1, 32, 96, 96, 1, true>
        <<<DHW1 / 256, 256, 0, stream>>>(PadA, wt_1, PadB, st1);
    finalize_stats<<<1, 64, 0, stream>>>(st1, g1, b1, 1.f / DHW1, af1);
    affine_pad<1><<<(DHW1 * 8 + 255) / 256, 256, 0, stream>>>(PadB, af1, DHW1 * 8);

    // stage D: conv (3,1,3) pad (1,0,1) -> PadA + stats
    convmm4<4, 64, 3, 1, 3, 1, 0, 1, 32, 96, 96, 1, true>
        <<<DHW1 / 256, 256, 0, stream>>>(PadB, wt_2, PadA, st2);
    finalize_stats<<<1, 64, 0, stream>>>(st2, g2, b2, 1.f / DHW1, af2);
    affine_pad<1><<<(DHW1 * 8 + 255) / 256, 256, 0, stream>>>(PadA, af2, DHW1 * 8);

    // stage E: conv (3,3,3) pad 1 -> PadB COMPACT + stats
    convmm4<4, 64, 3, 3, 3, 1, 1, 1, 32, 96, 96, 0, true>
        <<<DHW1 / 256, 256, 0, stream>>>(PadA, wt_3, PadB, st3);
    finalize_stats<<<1, 64, 0, stream>>>(st3, g3, b3, 1.f / DHW1, af3);

    final_out<<<DHW1 / 64, 256, 0, stream>>>(PadB, out, af3);
}